// Round 2
// baseline (2623.284 us; speedup 1.0000x reference)
//
#include <hip/hip_runtime.h>
#include <math.h>
#include <stdint.h>
#include <stddef.h>

#define AS1 __attribute__((address_space(1)))
#define AS3 __attribute__((address_space(3)))

typedef __attribute__((ext_vector_type(8))) __bf16 bf16x8;
typedef __attribute__((ext_vector_type(4))) float f32x4;

// Problem constants
#define SQ   256
#define BQ   32
#define EQ   300
#define HQ   2400
#define MQ   (SQ * BQ)      // 8192 rows
#define N3H  7200           // 3 gates
#define N2H  4800           // Z,F only (layer 3)
#define KP1  320            // padded E  (mult of 64)
#define KP2  2432           // padded H  (mult of 64)

// ---------- bf16 helpers (manual, RNE) ----------
__device__ __forceinline__ uint16_t f2bf(float x) {
    uint32_t u = __float_as_uint(x);
    u += 0x7FFFu + ((u >> 16) & 1u);
    return (uint16_t)(u >> 16);
}
__device__ __forceinline__ float bf2f(uint16_t b) {
    return __uint_as_float(((uint32_t)b) << 16);
}
__device__ __forceinline__ float sigm(float x) { return 1.f / (1.f + __expf(-x)); }

// ---------- fp32 -> (bf16 hi, bf16 lo) with zero K-padding ----------
__global__ void conv_split(const float* __restrict__ src, uint16_t* __restrict__ hi,
                           uint16_t* __restrict__ lo, int rows, int K, int Kp) {
    int idx = blockIdx.x * 256 + threadIdx.x;
    int total = rows * Kp;
    if (idx >= total) return;
    int r = idx / Kp;
    int k = idx - r * Kp;
    float v = 0.f;
    if (k < K) v = src[(size_t)r * K + k];
    uint16_t h = f2bf(v);
    hi[idx] = h;
    lo[idx] = f2bf(v - bf2f(h));
}

// zero the pad columns [HQ, KP2) of the X (hidden) split buffers, once per call
__global__ void zero_pad_X(uint16_t* __restrict__ hi, uint16_t* __restrict__ lo) {
    int idx = blockIdx.x * 256 + threadIdx.x;
    if (idx >= MQ * (KP2 - HQ)) return;
    int r = idx >> 5;                 // 32 pad cols
    int c = idx & 31;
    size_t off = (size_t)r * KP2 + HQ + c;
    hi[off] = 0;
    lo[off] = 0;
}

// ---------- split bf16 GEMM: Y[m][n] = sum_k A[m][k]*W[n][k]  (fp32-accurate) ----------
// Y = Ahi*Whi + Ahi*Wlo + Alo*Whi.  Tile 128x128, BK=64, 4 waves (2x2 of 64x64).
// A rows are absolute (rowbase + tile row); Y rows are chunk-local.
__global__ __launch_bounds__(256, 2) void gemm_split(
    const uint16_t* __restrict__ Ahi, const uint16_t* __restrict__ Alo,
    const uint16_t* __restrict__ Whi, const uint16_t* __restrict__ Wlo,
    float* __restrict__ Y, int Kp, int Ncols, int rowbase)
{
    __shared__ uint16_t lds[4][128][64];   // Ahi, Alo, Whi, Wlo tiles : 64 KiB
    const int tid  = threadIdx.x;
    const int lane = tid & 63;
    const int wave = tid >> 6;
    const int wm   = wave >> 1;            // wave row (0..1)
    const int wn   = wave & 1;             // wave col (0..1)
    const int lrow0 = blockIdx.y << 7;     // chunk-local A/Y row base
    const int col0  = blockIdx.x << 7;     // W row / Y col base

    // staging: each wave writes 8 rows x 128B per issue, lanes linear
    const int sr = (wave << 3) + (lane >> 3);   // row within 32-row group
    const int sk = (lane & 7) << 3;             // k element offset (8 bf16 = 16B)
    // fragment mapping (mfma_f32_16x16x32_bf16): m/n = lane&15, k = (lane>>4)*8
    const int fr = lane & 15;
    const int fk = (lane >> 4) << 3;

    f32x4 acc[4][4];
    f32x4 zero = {0.f, 0.f, 0.f, 0.f};
#pragma unroll
    for (int i = 0; i < 4; ++i)
#pragma unroll
        for (int j = 0; j < 4; ++j) acc[i][j] = zero;

    char* ldsb = (char*)&lds[0][0][0];

    for (int k0 = 0; k0 < Kp; k0 += 64) {
#pragma unroll
        for (int i = 0; i < 4; ++i) {
            const int rr = (i << 5) + sr;                        // 0..127 tile row
            const size_t ka = (size_t)(rowbase + lrow0 + rr) * Kp + (k0 + sk);
            const int wr = min(col0 + rr, Ncols - 1);            // clamp N tail
            const size_t kw = (size_t)wr * Kp + (k0 + sk);
            const int lofs = ((i << 5) + (wave << 3)) << 7;      // wave-uniform byte offset
            __builtin_amdgcn_global_load_lds((const AS1 uint32_t*)(Ahi + ka),
                                             (AS3 uint32_t*)(ldsb + lofs),         16, 0, 0);
            __builtin_amdgcn_global_load_lds((const AS1 uint32_t*)(Alo + ka),
                                             (AS3 uint32_t*)(ldsb + 16384 + lofs), 16, 0, 0);
            __builtin_amdgcn_global_load_lds((const AS1 uint32_t*)(Whi + kw),
                                             (AS3 uint32_t*)(ldsb + 32768 + lofs), 16, 0, 0);
            __builtin_amdgcn_global_load_lds((const AS1 uint32_t*)(Wlo + kw),
                                             (AS3 uint32_t*)(ldsb + 49152 + lofs), 16, 0, 0);
        }
        __syncthreads();   // drains vmcnt before barrier

#pragma unroll
        for (int kk = 0; kk < 2; ++kk) {
            bf16x8 ah[4], al[4], bh[4], bl[4];
#pragma unroll
            for (int t = 0; t < 4; ++t) {
                ah[t] = *(const bf16x8*)&lds[0][(wm << 6) + (t << 4) + fr][(kk << 5) + fk];
                al[t] = *(const bf16x8*)&lds[1][(wm << 6) + (t << 4) + fr][(kk << 5) + fk];
                bh[t] = *(const bf16x8*)&lds[2][(wn << 6) + (t << 4) + fr][(kk << 5) + fk];
                bl[t] = *(const bf16x8*)&lds[3][(wn << 6) + (t << 4) + fr][(kk << 5) + fk];
            }
#pragma unroll
            for (int mi = 0; mi < 4; ++mi)
#pragma unroll
                for (int ni = 0; ni < 4; ++ni) {
                    acc[mi][ni] = __builtin_amdgcn_mfma_f32_16x16x32_bf16(ah[mi], bh[ni], acc[mi][ni], 0, 0, 0);
                    acc[mi][ni] = __builtin_amdgcn_mfma_f32_16x16x32_bf16(ah[mi], bl[ni], acc[mi][ni], 0, 0, 0);
                    acc[mi][ni] = __builtin_amdgcn_mfma_f32_16x16x32_bf16(al[mi], bh[ni], acc[mi][ni], 0, 0, 0);
                }
        }
        __syncthreads();
    }

    // epilogue: D col = lane&15, row = (lane>>4)*4 + r   (chunk-local Y)
    const int orow = (lane >> 4) << 2;
    const int ocol = lane & 15;
#pragma unroll
    for (int mi = 0; mi < 4; ++mi) {
        const int r0 = lrow0 + (wm << 6) + (mi << 4) + orow;
#pragma unroll
        for (int ni = 0; ni < 4; ++ni) {
            const int c = col0 + (wn << 6) + (ni << 4) + ocol;
            if (c < Ncols) {
                float* yp = Y + (size_t)r0 * Ncols + c;
#pragma unroll
                for (int r = 0; r < 4; ++r) yp[(size_t)r * Ncols] = acc[mi][ni][r];
            }
        }
    }
}

// ---------- fo-pool scan chunk [s0, s0+Sc); carries cell state across chunks ----------
// MODE 0: layer1 (writes X, finals=c), MODE 1: layer2 (writes X, finals+=c),
// MODE 2: layer3 (Z,F only; fused output)
template<int MODE>
__global__ void scan_k(const float* __restrict__ Y, const float* __restrict__ bias,
                       uint16_t* __restrict__ hhi, uint16_t* __restrict__ hlo,
                       float* __restrict__ cst, float* __restrict__ fin,
                       float* __restrict__ out, const int* __restrict__ slen,
                       int s0, int Sc)
{
    int idx = blockIdx.x * 256 + threadIdx.x;
    if (idx >= BQ * HQ) return;
    int b = idx / HQ;
    int h = idx - b * HQ;
    const int Ncols = (MODE == 2) ? N2H : N3H;

    const float bz = bias[h], bfg = bias[HQ + h];
    const float bo = (MODE == 2) ? 0.f : bias[2 * HQ + h];
    float c = (s0 == 0) ? 0.f : cst[idx];
    const float* yp = Y + (size_t)b * Ncols + h;
    for (int si = 0; si < Sc; ++si) {
        const float* row = yp + (size_t)si * (BQ * Ncols);
        float z = tanhf(row[0] + bz);
        float f = sigm(row[HQ] + bfg);
        c = f * c + (1.f - f) * z;
        if (MODE != 2) {
            float o = sigm(row[2 * HQ] + bo);
            float hv = o * c;
            uint16_t hb = f2bf(hv);
            size_t off = ((size_t)(s0 + si) * BQ + b) * KP2 + h;
            hhi[off] = hb;
            hlo[off] = f2bf(hv - bf2f(hb));
        }
    }
    if (s0 + Sc < SQ) {
        cst[idx] = c;
    } else {
        if (MODE == 0)      fin[idx] = c;
        else if (MODE == 1) fin[idx] += c;
        else                out[idx] = (fin[idx] + c) / (float)slen[b];
    }
}

extern "C" void kernel_launch(void* const* d_in, const int* in_sizes, int n_in,
                              void* d_out, int out_size, void* d_ws, size_t ws_size,
                              hipStream_t stream) {
    const float* sent = (const float*)d_in[0];
    const int*   slen = (const int*)d_in[1];
    const float* Wl[3] = {(const float*)d_in[2], (const float*)d_in[4], (const float*)d_in[6]};
    const float* bl[3] = {(const float*)d_in[3], (const float*)d_in[5], (const float*)d_in[7]};
    float* out = (float*)d_out;

    // ws layout (fixed part ~153.4 MiB; Y chunk sized to fit ws_size)
    char* ws = (char*)d_ws;
    uint16_t* A1hi = (uint16_t*)ws;                    // [8192][320]
    uint16_t* A1lo = A1hi + (size_t)MQ * KP1;
    uint16_t* Xhi  = A1lo + (size_t)MQ * KP1;          // [8192][2432]
    uint16_t* Xlo  = Xhi  + (size_t)MQ * KP2;
    uint16_t* Whi  = Xlo  + (size_t)MQ * KP2;          // [7200][2432] max
    uint16_t* Wlo  = Whi  + (size_t)N3H * KP2;
    float*    cst  = (float*)(Wlo + (size_t)N3H * KP2);// [32][2400]
    float*    fin  = cst + (size_t)BQ * HQ;            // [32][2400]
    float*    Yc   = fin + (size_t)BQ * HQ;            // [Sc*32][7200] fp32

    const size_t fixed = (size_t)((char*)Yc - ws);
    int Sc = 4;
    const int sc_opts[7] = {256, 128, 64, 32, 16, 8, 4};
    for (int i = 0; i < 7; ++i) {
        size_t need = fixed + (size_t)sc_opts[i] * BQ * N3H * 4 + 256;
        if (need <= ws_size) { Sc = sc_opts[i]; break; }
    }

    conv_split<<<(MQ * KP1 + 255) / 256, 256, 0, stream>>>(sent, A1hi, A1lo, MQ, EQ, KP1);
    zero_pad_X<<<(MQ * 32 + 255) / 256, 256, 0, stream>>>(Xhi, Xlo);

    const int sgrid = (BQ * HQ + 255) / 256;
    for (int l = 0; l < 3; ++l) {
        const int Ncols = (l == 2) ? N2H : N3H;
        const int Kp    = (l == 0) ? KP1 : KP2;
        const int Ksrc  = (l == 0) ? EQ  : HQ;
        conv_split<<<(Ncols * Kp + 255) / 256, 256, 0, stream>>>(Wl[l], Whi, Wlo, Ncols, Ksrc, Kp);
        const uint16_t* Ah = (l == 0) ? A1hi : Xhi;
        const uint16_t* Al = (l == 0) ? A1lo : Xlo;
        dim3 gg((Ncols + 127) / 128, Sc / 4);
        for (int s0 = 0; s0 < SQ; s0 += Sc) {
            gemm_split<<<gg, 256, 0, stream>>>(Ah, Al, Whi, Wlo, Yc, Kp, Ncols, s0 * BQ);
            if (l == 0)
                scan_k<0><<<sgrid, 256, 0, stream>>>(Yc, bl[0], Xhi, Xlo, cst, fin, nullptr, nullptr, s0, Sc);
            else if (l == 1)
                scan_k<1><<<sgrid, 256, 0, stream>>>(Yc, bl[1], Xhi, Xlo, cst, fin, nullptr, nullptr, s0, Sc);
            else
                scan_k<2><<<sgrid, 256, 0, stream>>>(Yc, bl[2], nullptr, nullptr, cst, fin, out, slen, s0, Sc);
        }
    }
}